// Round 17
// baseline (2000.520 us; speedup 1.0000x reference)
//
#include <hip/hip_runtime.h>
#include <math.h>

typedef unsigned long long ull;

constexpr int Bn = 32, Tn = 64, Hn = 320, Jn = 320, Vn = 1024, Sn = 128;
constexpr int G4n = 1280, VP1 = 1025, WO4S = 1028;

// workspace layout (float units) -- ~13.9 MB
constexpr int OFF_XP  = 0;                        // 32*64*320
constexpr int OFF_G   = OFF_XP + Bn*Tn*Jn;        // 1024*1280
constexpr int OFF_WO4 = OFF_G + Vn*G4n;           // 80*1028*4
constexpr int OFF_WH4 = OFF_WO4 + 80*WO4S*4;      // 80*1280*4
constexpr int OFF_WP4 = OFF_WH4 + 80*G4n*4;       // 80*320*4
constexpr int OFF_CB  = OFF_WP4 + 80*Jn*4;        // 2*32*320 c (emit-parity)
constexpr int OFF_DEC = OFF_CB + 2*Bn*Hn;         // 2*32*320 dec (emit-parity)
constexpr int OFF_GB  = OFF_DEC + 2*Bn*Jn;        // 2*32*1280 gates (emit-parity)
constexpr int OFF_PB  = OFF_GB + 2*Bn*G4n;        // 2*32*8*1028 partial logits (step-parity)
constexpr int OFF_REC = OFF_PB + 2*Bn*8*1028;     // 2*32*4 int (step-parity)

__device__ __forceinline__ float sigmf(float x) { return 1.0f / (1.0f + expf(-x)); }

// monotonic (value,idx) pack: bigger float -> bigger key; tie -> smaller idx wins
__device__ __forceinline__ ull pack_key(float v, int idx) {
    unsigned u = __float_as_uint(v);
    u = (u & 0x80000000u) ? ~u : (u | 0x80000000u);
    return ((ull)u << 32) | (unsigned)(0x7FFFFFFF - idx);
}
__device__ __forceinline__ float key_val(ull k) {
    unsigned u = (unsigned)(k >> 32);
    return __uint_as_float((u & 0x80000000u) ? (u & 0x7FFFFFFFu) : ~u);
}
__device__ __forceinline__ int key_idx(ull k) { return 0x7FFFFFFF - (int)(k & 0xFFFFFFFFu); }

// ------- 64x64 f32 GEMM tile, BK=32, float4-coalesced staging -------
// As stride 73: A-write banks (4kq + 9j) distinct within a wave row-group.
__device__ __forceinline__ void gemm_tile(const float* __restrict__ A,
                                          const float* __restrict__ Bm,
                                          const float* __restrict__ bias,
                                          float* __restrict__ C,
                                          int N, int K, int bx, int by,
                                          float (*As)[73], float (*Bs)[68]) {
    const int tx = threadIdx.x & 15, ty = threadIdx.x >> 4;
    const int n0 = bx * 64, m0 = by * 64;
    float acc[4][4] = {};
    for (int k0 = 0; k0 < K; k0 += 32) {
        // stage A: 64 rows x 32 k (128B/row) = 512 float4, 2 per thread
        for (int i = threadIdx.x; i < 512; i += 256) {
            const int mm = i >> 3, kq = (i & 7) << 2;
            float4 v = *(const float4*)(A + (size_t)(m0 + mm) * K + k0 + kq);
            As[kq][mm] = v.x; As[kq + 1][mm] = v.y;
            As[kq + 2][mm] = v.z; As[kq + 3][mm] = v.w;
        }
        // stage B: 32 rows x 64 cols = 512 float4, aligned LDS float4 stores
        for (int i = threadIdx.x; i < 512; i += 256) {
            const int kk = i >> 4, q = (i & 15) << 2;
            float4 v = *(const float4*)(Bm + (size_t)(k0 + kk) * N + n0 + q);
            *(float4*)&Bs[kk][q] = v;
        }
        __syncthreads();
#pragma unroll
        for (int kk = 0; kk < 32; ++kk) {
            float av[4], bv[4];
#pragma unroll
            for (int r = 0; r < 4; ++r) { av[r] = As[kk][ty * 4 + r]; bv[r] = Bs[kk][tx * 4 + r]; }
#pragma unroll
            for (int i2 = 0; i2 < 4; ++i2)
#pragma unroll
                for (int j2 = 0; j2 < 4; ++j2) acc[i2][j2] += av[i2] * bv[j2];
        }
        __syncthreads();
    }
#pragma unroll
    for (int i2 = 0; i2 < 4; ++i2)
#pragma unroll
        for (int j2 = 0; j2 < 4; ++j2)
            C[(size_t)(m0 + ty * 4 + i2) * N + n0 + tx * 4 + j2] =
                acc[i2][j2] + bias[n0 + tx * 4 + j2];
}

// ---------------- fused preamble: both GEMMs + 3 repacks in ONE launch ----------------
__global__ __launch_bounds__(256) void preamble(
    const float* __restrict__ x, const float* __restrict__ W_enc,
    const float* __restrict__ b_enc, const float* __restrict__ Emb,
    const float* __restrict__ W_ih, const float* __restrict__ b_lstm,
    const float* __restrict__ W_hh, const float* __restrict__ W_pred,
    const float* __restrict__ W_out,
    float* __restrict__ xp, float* __restrict__ Gm,
    float* __restrict__ Wo4, float* __restrict__ Wh4, float* __restrict__ Wp4) {
    __shared__ float As[32][73];
    __shared__ float Bs[32][68];
    const int blk = blockIdx.x;
    if (blk < 160) {
        // xp = x @ W_enc + b_enc : M=2048, N=320 (5 x 64), K=1024
        gemm_tile(x, W_enc, b_enc, xp, Jn, 1024, blk % 5, blk / 5, As, Bs);
    } else if (blk < 480) {
        // Gm = Emb @ W_ih + b_lstm : M=1024, N=1280 (20 x 64), K=320
        const int t = blk - 160;
        gemm_tile(Emb, W_ih, b_lstm, Gm, G4n, Hn, t % 20, t / 20, As, Bs);
    } else if (blk < 560) {
        const int k4 = blk - 480;
        for (int c = threadIdx.x; c < VP1; c += 256) {
            float4 v;
            v.x = W_out[(k4 * 4 + 0) * VP1 + c];
            v.y = W_out[(k4 * 4 + 1) * VP1 + c];
            v.z = W_out[(k4 * 4 + 2) * VP1 + c];
            v.w = W_out[(k4 * 4 + 3) * VP1 + c];
            ((float4*)Wo4)[(size_t)k4 * WO4S + c] = v;
        }
    } else if (blk < 640) {
        const int k4 = blk - 560;
        for (int c = threadIdx.x; c < G4n; c += 256) {
            float4 v;
            v.x = W_hh[(k4 * 4 + 0) * G4n + c];
            v.y = W_hh[(k4 * 4 + 1) * G4n + c];
            v.z = W_hh[(k4 * 4 + 2) * G4n + c];
            v.w = W_hh[(k4 * 4 + 3) * G4n + c];
            ((float4*)Wh4)[(size_t)k4 * G4n + c] = v;
        }
    } else {
        const int k4 = blk - 640;
        for (int c = threadIdx.x; c < Jn; c += 256) {
            float4 v;
            v.x = W_pred[(k4 * 4 + 0) * Jn + c];
            v.y = W_pred[(k4 * 4 + 1) * Jn + c];
            v.z = W_pred[(k4 * 4 + 2) * Jn + c];
            v.w = W_pred[(k4 * 4 + 3) * Jn + c];
            ((float4*)Wp4)[(size_t)k4 * Jn + c] = v;
        }
    }
}

// ---------------- one decode step per launch; 8 WGs per batch element ----------------
// K-sliced partial logits; frozen groups exit before any GEMV/reduce work.
__global__ __launch_bounds__(320, 1) void rnnt_step(
    const float* __restrict__ xp, const float* __restrict__ Gm,
    const float* __restrict__ Wo4, const float* __restrict__ Wh4,
    const float* __restrict__ Wp4,
    const float* __restrict__ b_out, const float* __restrict__ b_lstm,
    const float* __restrict__ b_pred, const int* __restrict__ out_len,
    float* __restrict__ cb, float* __restrict__ db, float* __restrict__ gb,
    float* __restrict__ pb, int* __restrict__ rec, float* __restrict__ out,
    int L) {
    __shared__ __align__(16) float h_s[Hn];
    __shared__ __align__(16) float f_s[48];
    __shared__ float dec_s[40];
    __shared__ ull wk_s[5];

    const int w = blockIdx.x, tid = threadIdx.x;
    const int b = w & 31, m = w >> 5;
    const int ol = out_len[b];
    const float4* Wo4f = (const float4*)Wo4;
    const float4* Wh4f = (const float4*)Wh4;
    const float4* Wp4f = (const float4*)Wp4;
    const float4* h4 = (const float4*)h_s;

    int tnew, genN;
    bool doDec;
    if (L == 0) {
        // prologue: h0,c0 (one row per thread); c0 slice store; rec[parity 0]
        float c0 = sigmf(b_lstm[tid]) * tanhf(b_lstm[2 * Hn + tid]);
        float h0 = sigmf(b_lstm[3 * Hn + tid]) * tanhf(c0);
        h_s[tid] = h0;
        int lc = tid - m * 40;
        if (lc >= 0 && lc < 40) cb[b * Hn + tid] = c0;
        if (m == 0 && tid == 0) {
            int* rn = rec + b * 4;
            rn[0] = 0; rn[1] = 0; rn[2] = 0;
        }
        tnew = 0; genN = 0; doDec = true;
        __syncthreads();
    } else {
        const int* rp = rec + ((L - 1) & 1) * Bn * 4 + b * 4;
        const int told = rp[0], sold = rp[1], len = rp[2];
        // ---- frozen fast path: fixed outputs, no reduce/GEMV ----
        if (told >= ol) {
            if (m == 0 && tid == 0) {
                out[(L - 1) * Bn + b] = 1024.0f;
                out[Sn * Bn + (L - 1) * Bn + b] = 0.0f;
                out[2 * Sn * Bn + (L - 1) * Bn + b] = (float)told;
                int* rn = rec + (L & 1) * Bn * 4 + b * 4;
                rn[0] = told; rn[1] = 0; rn[2] = len;
                if (L == Sn) out[3 * Sn * Bn + b] = (float)len;
            }
            return;
        }
        // prefetch LSTM inputs (overlap with partial-logit reduce)
        const float* gq = gb + (size_t)((len & 1) * Bn + b) * G4n;
        const float* cv = cb + (size_t)((len & 1) * Bn + b) * Hn;
        float g0 = gq[tid], g1 = gq[Hn + tid], g2 = gq[2 * Hn + tid], g3 = gq[3 * Hn + tid];
        float crv = cv[tid];
        asm volatile("" ::: "memory");
        // ---- replicated decode: float4 sum of 8 partial rows, argmax ----
        const float4* pp4 = (const float4*)(pb + (size_t)(((L - 1) & 1) * Bn + b) * 8 * 1028);
        ull key = 0;
        if (tid < 257) {
            float4 sv = make_float4(0.f, 0.f, 0.f, 0.f);
#pragma unroll
            for (int mm = 0; mm < 8; ++mm) {
                float4 v = pp4[mm * 257 + tid];
                sv.x += v.x; sv.y += v.y; sv.z += v.z; sv.w += v.w;
            }
            const int c0 = tid * 4;
            key = pack_key(sv.x + b_out[c0], c0);
            if (c0 + 1 < VP1) { ull k2 = pack_key(sv.y + b_out[c0 + 1], c0 + 1); if (k2 > key) key = k2; }
            if (c0 + 2 < VP1) { ull k2 = pack_key(sv.z + b_out[c0 + 2], c0 + 2); if (k2 > key) key = k2; }
            if (c0 + 3 < VP1) { ull k2 = pack_key(sv.w + b_out[c0 + 3], c0 + 3); if (k2 > key) key = k2; }
        }
#pragma unroll
        for (int d = 1; d < 64; d <<= 1) {
            ull o = __shfl_xor(key, d, 64);
            if (o > key) key = o;
        }
        if ((tid & 63) == 0) wk_s[tid >> 6] = key;
        __syncthreads();
        ull bk = wk_s[0];
#pragma unroll
        for (int i = 1; i < 5; ++i) if (wk_s[i] > bk) bk = wk_s[i];
        const int label = key_idx(bk);
        const bool emit = (label != Vn);          // told < ol guaranteed here
        int sym2 = emit ? sold + 1 : 0;
        const bool force = emit && (sym2 >= 2);
        const bool advance = (!emit) || force;
        tnew = told + (advance ? 1 : 0);
        sym2 = advance ? 0 : sym2;
        const int newlen = len + (emit ? 1 : 0);
        if (m == 0 && tid == 0) {
            out[(L - 1) * Bn + b] = emit ? (float)label : 1024.0f;
            out[Sn * Bn + (L - 1) * Bn + b] = key_val(bk);
            out[2 * Sn * Bn + (L - 1) * Bn + b] = (float)told;
            int* rn = rec + (L & 1) * Bn * 4 + b * 4;
            rn[0] = tnew; rn[1] = sym2; rn[2] = newlen;
            if (L == Sn) out[3 * Sn * Bn + b] = (float)newlen;
        }
        if (L == Sn) return;
        if (tnew >= ol) return;   // newly frozen: later launches take the fast path
        genN = newlen;
        doDec = emit;
        if (emit) {
            const float* gE = Gm + (size_t)label * G4n;
            float xi = g0 + gE[tid];
            float xf = g1 + gE[Hn + tid];
            float xg = g2 + gE[2 * Hn + tid];
            float xo = g3 + gE[3 * Hn + tid];
            float c2 = sigmf(xf) * crv + sigmf(xi) * tanhf(xg);
            float h2 = sigmf(xo) * tanhf(c2);
            h_s[tid] = h2;
            int lc = tid - m * 40;
            if (lc >= 0 && lc < 40)
                cb[(size_t)((newlen & 1) * Bn + b) * Hn + tid] = c2;
        } else {
            if (tid < 40)
                dec_s[tid] = db[(size_t)((len & 1) * Bn + b) * Jn + m * 40 + tid];
        }
        __syncthreads();   // h_s (emit) / dec_s (blank) ready
    }
    // ---- phase 2 (h changed): gates 2-thr/col k-split; dec 4-thr/col k-split ----
    if (doDec) {
        {   // gates: all 320 threads, 40 loads deep
            const int cl = tid >> 1, kh = tid & 1;
            const int c = m * 160 + cl;
            float ax = 0.f, ay = 0.f, az = 0.f, aw = 0.f;
#pragma unroll 20
            for (int k4 = kh * 40; k4 < kh * 40 + 40; ++k4) {
                float4 wv = Wh4f[(size_t)k4 * G4n + c];
                float4 hv = h4[k4];
                ax += wv.x * hv.x; ay += wv.y * hv.y;
                az += wv.z * hv.z; aw += wv.w * hv.w;
            }
            float part = ax + ay + az + aw;
            part += __shfl_xor(part, 1, 64);
            if (kh == 0)
                gb[(size_t)((genN & 1) * Bn + b) * G4n + c] = part;
        }
        if (tid < 160) {   // dec: 4 threads per col, 20 loads deep
            const int sc = tid >> 2, kk2 = tid & 3;
            const int c = m * 40 + sc;
            float ax = 0.f, ay = 0.f, az = 0.f, aw = 0.f;
#pragma unroll 20
            for (int k4 = kk2 * 20; k4 < kk2 * 20 + 20; ++k4) {
                float4 wv = Wp4f[(size_t)k4 * Jn + c];
                float4 hv = h4[k4];
                ax += wv.x * hv.x; ay += wv.y * hv.y;
                az += wv.z * hv.z; aw += wv.w * hv.w;
            }
            float part = ax + ay + az + aw;
            part += __shfl_xor(part, 1, 64);
            part += __shfl_xor(part, 2, 64);
            if (kk2 == 0) {
                float d = part + b_pred[c];
                dec_s[sc] = d;
                db[(size_t)((genN & 1) * Bn + b) * Jn + c] = d;
            }
        }
        __syncthreads();   // dec_s ready
    }
    // ---- f slice: own 40 components ----
    if (tid < 40) {
        const int tc = tnew < (Tn - 1) ? tnew : (Tn - 1);
        f_s[tid] = fmaxf(xp[(size_t)(b * Tn + tc) * Jn + m * 40 + tid] + dec_s[tid], 0.0f);
    }
    __syncthreads();   // f_s ready
    // ---- partial logits over own k-slice, ALL 1025 columns ----
    {
        const float4* f4 = (const float4*)f_s;
        float4 fr[10];
#pragma unroll
        for (int j = 0; j < 10; ++j) fr[j] = f4[j];
        float* pw = pb + (size_t)((L & 1) * Bn + b) * 8 * 1028 + m * 1028;
        for (int c = tid; c < VP1; c += 320) {
            float ax = 0.f, ay = 0.f, az = 0.f, aw = 0.f;
#pragma unroll
            for (int j = 0; j < 10; ++j) {
                float4 wv = Wo4f[(size_t)(10 * m + j) * WO4S + c];
                float4 fv = fr[j];
                ax += wv.x * fv.x; ay += wv.y * fv.y;
                az += wv.z * fv.z; aw += wv.w * fv.w;
            }
            pw[c] = ax + ay + az + aw;
        }
    }
}

extern "C" void kernel_launch(void* const* d_in, const int* in_sizes, int n_in,
                              void* d_out, int out_size, void* d_ws, size_t ws_size,
                              hipStream_t stream) {
    (void)in_sizes; (void)n_in; (void)out_size; (void)ws_size;
    const float* x      = (const float*)d_in[0];
    const int*   outlen = (const int*)d_in[1];
    const float* W_enc  = (const float*)d_in[2];
    const float* b_enc  = (const float*)d_in[3];
    const float* Emb    = (const float*)d_in[4];
    const float* W_ih   = (const float*)d_in[5];
    const float* W_hh   = (const float*)d_in[6];
    const float* b_lstm = (const float*)d_in[7];
    const float* W_pred = (const float*)d_in[8];
    const float* b_pred = (const float*)d_in[9];
    const float* W_out  = (const float*)d_in[10];
    const float* b_out  = (const float*)d_in[11];

    float* ws  = (float*)d_ws;
    float* xp  = ws + OFF_XP;
    float* Gm  = ws + OFF_G;
    float* Wo4 = ws + OFF_WO4;
    float* Wh4 = ws + OFF_WH4;
    float* Wp4 = ws + OFF_WP4;
    float* cb  = ws + OFF_CB;
    float* db  = ws + OFF_DEC;
    float* gb  = ws + OFF_GB;
    float* pb  = ws + OFF_PB;
    int*   rec = (int*)(ws + OFF_REC);

    preamble<<<720, 256, 0, stream>>>(x, W_enc, b_enc, Emb, W_ih, b_lstm,
                                      W_hh, W_pred, W_out,
                                      xp, Gm, Wo4, Wh4, Wp4);

    for (int L = 0; L <= Sn; ++L)
        rnnt_step<<<256, 320, 0, stream>>>(xp, Gm, Wo4, Wh4, Wp4,
                                           b_out, b_lstm, b_pred, outlen,
                                           cb, db, gb, pb, rec,
                                           (float*)d_out, L);
}

// Round 18
// 1887.974 us; speedup vs baseline: 1.0596x; 1.0596x over previous
//
#include <hip/hip_runtime.h>
#include <math.h>

typedef unsigned long long ull;

constexpr int Bn = 32, Tn = 64, Hn = 320, Jn = 320, Vn = 1024, Sn = 128;
constexpr int G4n = 1280, VP1 = 1025, WO4S = 1028;

// workspace layout (float units) -- ~13.9 MB
constexpr int OFF_XP  = 0;                        // 32*64*320
constexpr int OFF_G   = OFF_XP + Bn*Tn*Jn;        // 1024*1280
constexpr int OFF_WO4 = OFF_G + Vn*G4n;           // 80*1028*4
constexpr int OFF_WH4 = OFF_WO4 + 80*WO4S*4;      // 80*1280*4
constexpr int OFF_WP4 = OFF_WH4 + 80*G4n*4;       // 80*320*4
constexpr int OFF_CB  = OFF_WP4 + 80*Jn*4;        // 2*32*320 c (emit-parity)
constexpr int OFF_DEC = OFF_CB + 2*Bn*Hn;         // 2*32*320 dec (emit-parity)
constexpr int OFF_GB  = OFF_DEC + 2*Bn*Jn;        // 2*32*1280 gates (emit-parity)
constexpr int OFF_PB  = OFF_GB + 2*Bn*G4n;        // 2*32*8*1028 partial logits (step-parity)
constexpr int OFF_REC = OFF_PB + 2*Bn*8*1028;     // 2*32*4 int (step-parity)

__device__ __forceinline__ float sigmf(float x) { return 1.0f / (1.0f + expf(-x)); }

// monotonic (value,idx) pack: bigger float -> bigger key; tie -> smaller idx wins
__device__ __forceinline__ ull pack_key(float v, int idx) {
    unsigned u = __float_as_uint(v);
    u = (u & 0x80000000u) ? ~u : (u | 0x80000000u);
    return ((ull)u << 32) | (unsigned)(0x7FFFFFFF - idx);
}
__device__ __forceinline__ float key_val(ull k) {
    unsigned u = (unsigned)(k >> 32);
    return __uint_as_float((u & 0x80000000u) ? (u & 0x7FFFFFFFu) : ~u);
}
__device__ __forceinline__ int key_idx(ull k) { return 0x7FFFFFFF - (int)(k & 0xFFFFFFFFu); }

// ------- 64x64 f32 GEMM tile, BK=32, float4-coalesced staging (0 bank conflicts) -------
__device__ __forceinline__ void gemm_tile(const float* __restrict__ A,
                                          const float* __restrict__ Bm,
                                          const float* __restrict__ bias,
                                          float* __restrict__ C,
                                          int N, int K, int bx, int by,
                                          float (*As)[73], float (*Bs)[68]) {
    const int tx = threadIdx.x & 15, ty = threadIdx.x >> 4;
    const int n0 = bx * 64, m0 = by * 64;
    float acc[4][4] = {};
    for (int k0 = 0; k0 < K; k0 += 32) {
        for (int i = threadIdx.x; i < 512; i += 256) {
            const int mm = i >> 3, kq = (i & 7) << 2;
            float4 v = *(const float4*)(A + (size_t)(m0 + mm) * K + k0 + kq);
            As[kq][mm] = v.x; As[kq + 1][mm] = v.y;
            As[kq + 2][mm] = v.z; As[kq + 3][mm] = v.w;
        }
        for (int i = threadIdx.x; i < 512; i += 256) {
            const int kk = i >> 4, q = (i & 15) << 2;
            float4 v = *(const float4*)(Bm + (size_t)(k0 + kk) * N + n0 + q);
            *(float4*)&Bs[kk][q] = v;
        }
        __syncthreads();
#pragma unroll
        for (int kk = 0; kk < 32; ++kk) {
            float av[4], bv[4];
#pragma unroll
            for (int r = 0; r < 4; ++r) { av[r] = As[kk][ty * 4 + r]; bv[r] = Bs[kk][tx * 4 + r]; }
#pragma unroll
            for (int i2 = 0; i2 < 4; ++i2)
#pragma unroll
                for (int j2 = 0; j2 < 4; ++j2) acc[i2][j2] += av[i2] * bv[j2];
        }
        __syncthreads();
    }
#pragma unroll
    for (int i2 = 0; i2 < 4; ++i2)
#pragma unroll
        for (int j2 = 0; j2 < 4; ++j2)
            C[(size_t)(m0 + ty * 4 + i2) * N + n0 + tx * 4 + j2] =
                acc[i2][j2] + bias[n0 + tx * 4 + j2];
}

// ---------------- fused preamble: both GEMMs + 3 repacks in ONE launch ----------------
__global__ __launch_bounds__(256) void preamble(
    const float* __restrict__ x, const float* __restrict__ W_enc,
    const float* __restrict__ b_enc, const float* __restrict__ Emb,
    const float* __restrict__ W_ih, const float* __restrict__ b_lstm,
    const float* __restrict__ W_hh, const float* __restrict__ W_pred,
    const float* __restrict__ W_out,
    float* __restrict__ xp, float* __restrict__ Gm,
    float* __restrict__ Wo4, float* __restrict__ Wh4, float* __restrict__ Wp4) {
    __shared__ float As[32][73];
    __shared__ float Bs[32][68];
    const int blk = blockIdx.x;
    if (blk < 160) {
        gemm_tile(x, W_enc, b_enc, xp, Jn, 1024, blk % 5, blk / 5, As, Bs);
    } else if (blk < 480) {
        const int t = blk - 160;
        gemm_tile(Emb, W_ih, b_lstm, Gm, G4n, Hn, t % 20, t / 20, As, Bs);
    } else if (blk < 560) {
        const int k4 = blk - 480;
        for (int c = threadIdx.x; c < VP1; c += 256) {
            float4 v;
            v.x = W_out[(k4 * 4 + 0) * VP1 + c];
            v.y = W_out[(k4 * 4 + 1) * VP1 + c];
            v.z = W_out[(k4 * 4 + 2) * VP1 + c];
            v.w = W_out[(k4 * 4 + 3) * VP1 + c];
            ((float4*)Wo4)[(size_t)k4 * WO4S + c] = v;
        }
    } else if (blk < 640) {
        const int k4 = blk - 560;
        for (int c = threadIdx.x; c < G4n; c += 256) {
            float4 v;
            v.x = W_hh[(k4 * 4 + 0) * G4n + c];
            v.y = W_hh[(k4 * 4 + 1) * G4n + c];
            v.z = W_hh[(k4 * 4 + 2) * G4n + c];
            v.w = W_hh[(k4 * 4 + 3) * G4n + c];
            ((float4*)Wh4)[(size_t)k4 * G4n + c] = v;
        }
    } else {
        const int k4 = blk - 640;
        for (int c = threadIdx.x; c < Jn; c += 256) {
            float4 v;
            v.x = W_pred[(k4 * 4 + 0) * Jn + c];
            v.y = W_pred[(k4 * 4 + 1) * Jn + c];
            v.z = W_pred[(k4 * 4 + 2) * Jn + c];
            v.w = W_pred[(k4 * 4 + 3) * Jn + c];
            ((float4*)Wp4)[(size_t)k4 * Jn + c] = v;
        }
    }
}

// ---------------- one decode step per launch; 8 WGs per batch element ----------------
// K-sliced partial logits; frozen groups exit before any GEMV/reduce work.
__global__ __launch_bounds__(320, 1) void rnnt_step(
    const float* __restrict__ xp, const float* __restrict__ Gm,
    const float* __restrict__ Wo4, const float* __restrict__ Wh4,
    const float* __restrict__ Wp4,
    const float* __restrict__ b_out, const float* __restrict__ b_lstm,
    const float* __restrict__ b_pred, const int* __restrict__ out_len,
    float* __restrict__ cb, float* __restrict__ db, float* __restrict__ gb,
    float* __restrict__ pb, int* __restrict__ rec, float* __restrict__ out,
    int L) {
    __shared__ __align__(16) float h_s[Hn];
    __shared__ __align__(16) float f_s[48];
    __shared__ float dec_s[40];
    __shared__ ull wk_s[5];

    const int w = blockIdx.x, tid = threadIdx.x;
    const int b = w & 31, m = w >> 5;
    const int ol = out_len[b];
    const float4* Wo4f = (const float4*)Wo4;
    const float4* Wh4f = (const float4*)Wh4;
    const float4* Wp4f = (const float4*)Wp4;
    const float4* h4 = (const float4*)h_s;

    int tnew, genN;
    bool doDec;
    if (L == 0) {
        float c0 = sigmf(b_lstm[tid]) * tanhf(b_lstm[2 * Hn + tid]);
        float h0 = sigmf(b_lstm[3 * Hn + tid]) * tanhf(c0);
        h_s[tid] = h0;
        int lc = tid - m * 40;
        if (lc >= 0 && lc < 40) cb[b * Hn + tid] = c0;
        if (m == 0 && tid == 0) {
            int* rn = rec + b * 4;
            rn[0] = 0; rn[1] = 0; rn[2] = 0;
        }
        tnew = 0; genN = 0; doDec = true;
        __syncthreads();
    } else {
        const int4 rp = *(const int4*)(rec + ((L - 1) & 1) * Bn * 4 + b * 4);
        const int told = rp.x, sold = rp.y, len = rp.z;
        // ---- frozen fast path ----
        if (told >= ol) {
            if (m == 0 && tid == 0) {
                out[(L - 1) * Bn + b] = 1024.0f;
                out[Sn * Bn + (L - 1) * Bn + b] = 0.0f;
                out[2 * Sn * Bn + (L - 1) * Bn + b] = (float)told;
                int* rn = rec + (L & 1) * Bn * 4 + b * 4;
                rn[0] = told; rn[1] = 0; rn[2] = len;
                if (L == Sn) out[3 * Sn * Bn + b] = (float)len;
            }
            return;
        }
        // prefetch LSTM inputs (overlap with partial-logit reduce)
        const float* gq = gb + (size_t)((len & 1) * Bn + b) * G4n;
        const float* cv = cb + (size_t)((len & 1) * Bn + b) * Hn;
        float g0 = gq[tid], g1 = gq[Hn + tid], g2 = gq[2 * Hn + tid], g3 = gq[3 * Hn + tid];
        float crv = cv[tid];
        asm volatile("" ::: "memory");
        // ---- replicated decode: float4 sum of 8 partial rows, argmax ----
        const float4* pp4 = (const float4*)(pb + (size_t)(((L - 1) & 1) * Bn + b) * 8 * 1028);
        ull key = 0;
        if (tid < 257) {
            float4 sv = make_float4(0.f, 0.f, 0.f, 0.f);
#pragma unroll
            for (int mm = 0; mm < 8; ++mm) {
                float4 v = pp4[mm * 257 + tid];
                sv.x += v.x; sv.y += v.y; sv.z += v.z; sv.w += v.w;
            }
            const int c0 = tid * 4;
            key = pack_key(sv.x + b_out[c0], c0);
            if (c0 + 1 < VP1) { ull k2 = pack_key(sv.y + b_out[c0 + 1], c0 + 1); if (k2 > key) key = k2; }
            if (c0 + 2 < VP1) { ull k2 = pack_key(sv.z + b_out[c0 + 2], c0 + 2); if (k2 > key) key = k2; }
            if (c0 + 3 < VP1) { ull k2 = pack_key(sv.w + b_out[c0 + 3], c0 + 3); if (k2 > key) key = k2; }
        }
#pragma unroll
        for (int d = 1; d < 64; d <<= 1) {
            ull o = __shfl_xor(key, d, 64);
            if (o > key) key = o;
        }
        if ((tid & 63) == 0) wk_s[tid >> 6] = key;
        __syncthreads();
        ull bk = wk_s[0];
#pragma unroll
        for (int i = 1; i < 5; ++i) if (wk_s[i] > bk) bk = wk_s[i];
        const int label = key_idx(bk);
        const bool emit = (label != Vn);          // told < ol guaranteed here
        int sym2 = emit ? sold + 1 : 0;
        const bool force = emit && (sym2 >= 2);
        const bool advance = (!emit) || force;
        tnew = told + (advance ? 1 : 0);
        sym2 = advance ? 0 : sym2;
        const int newlen = len + (emit ? 1 : 0);
        if (m == 0 && tid == 0) {
            out[(L - 1) * Bn + b] = emit ? (float)label : 1024.0f;
            out[Sn * Bn + (L - 1) * Bn + b] = key_val(bk);
            out[2 * Sn * Bn + (L - 1) * Bn + b] = (float)told;
            int* rn = rec + (L & 1) * Bn * 4 + b * 4;
            rn[0] = tnew; rn[1] = sym2; rn[2] = newlen;
            if (L == Sn) out[3 * Sn * Bn + b] = (float)newlen;
        }
        if (L == Sn) return;
        if (tnew >= ol) return;   // newly frozen
        genN = newlen;
        doDec = emit;
        if (emit) {
            const float* gE = Gm + (size_t)label * G4n;
            float xi = g0 + gE[tid];
            float xf = g1 + gE[Hn + tid];
            float xg = g2 + gE[2 * Hn + tid];
            float xo = g3 + gE[3 * Hn + tid];
            float c2 = sigmf(xf) * crv + sigmf(xi) * tanhf(xg);
            float h2 = sigmf(xo) * tanhf(c2);
            h_s[tid] = h2;
            int lc = tid - m * 40;
            if (lc >= 0 && lc < 40)
                cb[(size_t)((newlen & 1) * Bn + b) * Hn + tid] = c2;
        } else {
            if (tid < 40)
                dec_s[tid] = db[(size_t)((len & 1) * Bn + b) * Jn + m * 40 + tid];
        }
        __syncthreads();   // h_s (emit) / dec_s (blank) ready
    }
    // ---- phase 2 (h changed): gates slice (160 thr) + dec slice (40 thr) ----
    if (doDec) {
        if (tid < 160) {
            const int c = m * 160 + tid;
            float ax = 0.f, ay = 0.f, az = 0.f, aw = 0.f;
#pragma unroll 20
            for (int k4 = 0; k4 < 80; ++k4) {
                float4 wv = Wh4f[(size_t)k4 * G4n + c];
                float4 hv = h4[k4];
                ax += wv.x * hv.x; ay += wv.y * hv.y;
                az += wv.z * hv.z; aw += wv.w * hv.w;
            }
            gb[(size_t)((genN & 1) * Bn + b) * G4n + c] = ax + ay + az + aw;
        } else if (tid < 200) {
            const int lc = tid - 160;
            const int c = m * 40 + lc;
            float ax = 0.f, ay = 0.f, az = 0.f, aw = 0.f;
#pragma unroll 20
            for (int k4 = 0; k4 < 80; ++k4) {
                float4 wv = Wp4f[(size_t)k4 * Jn + c];
                float4 hv = h4[k4];
                ax += wv.x * hv.x; ay += wv.y * hv.y;
                az += wv.z * hv.z; aw += wv.w * hv.w;
            }
            float d = b_pred[c] + ax + ay + az + aw;
            dec_s[lc] = d;
            db[(size_t)((genN & 1) * Bn + b) * Jn + c] = d;
        }
        __syncthreads();   // dec_s ready
    }
    // ---- f slice: own 40 components ----
    if (tid < 40) {
        const int tc = tnew < (Tn - 1) ? tnew : (Tn - 1);
        f_s[tid] = fmaxf(xp[(size_t)(b * Tn + tc) * Jn + m * 40 + tid] + dec_s[tid], 0.0f);
    }
    __syncthreads();   // f_s ready
    // ---- partial logits over own k-slice, ALL 1025 columns ----
    {
        const float4* f4 = (const float4*)f_s;
        float4 fr[10];
#pragma unroll
        for (int j = 0; j < 10; ++j) fr[j] = f4[j];
        float* pw = pb + (size_t)((L & 1) * Bn + b) * 8 * 1028 + m * 1028;
        for (int c = tid; c < VP1; c += 320) {
            float ax = 0.f, ay = 0.f, az = 0.f, aw = 0.f;
#pragma unroll
            for (int j = 0; j < 10; ++j) {
                float4 wv = Wo4f[(size_t)(10 * m + j) * WO4S + c];
                float4 fv = fr[j];
                ax += wv.x * fv.x; ay += wv.y * fv.y;
                az += wv.z * fv.z; aw += wv.w * fv.w;
            }
            pw[c] = ax + ay + az + aw;
        }
    }
}

extern "C" void kernel_launch(void* const* d_in, const int* in_sizes, int n_in,
                              void* d_out, int out_size, void* d_ws, size_t ws_size,
                              hipStream_t stream) {
    (void)in_sizes; (void)n_in; (void)out_size; (void)ws_size;
    const float* x      = (const float*)d_in[0];
    const int*   outlen = (const int*)d_in[1];
    const float* W_enc  = (const float*)d_in[2];
    const float* b_enc  = (const float*)d_in[3];
    const float* Emb    = (const float*)d_in[4];
    const float* W_ih   = (const float*)d_in[5];
    const float* W_hh   = (const float*)d_in[6];
    const float* b_lstm = (const float*)d_in[7];
    const float* W_pred = (const float*)d_in[8];
    const float* b_pred = (const float*)d_in[9];
    const float* W_out  = (const float*)d_in[10];
    const float* b_out  = (const float*)d_in[11];

    float* ws  = (float*)d_ws;
    float* xp  = ws + OFF_XP;
    float* Gm  = ws + OFF_G;
    float* Wo4 = ws + OFF_WO4;
    float* Wh4 = ws + OFF_WH4;
    float* Wp4 = ws + OFF_WP4;
    float* cb  = ws + OFF_CB;
    float* db  = ws + OFF_DEC;
    float* gb  = ws + OFF_GB;
    float* pb  = ws + OFF_PB;
    int*   rec = (int*)(ws + OFF_REC);

    preamble<<<720, 256, 0, stream>>>(x, W_enc, b_enc, Emb, W_ih, b_lstm,
                                      W_hh, W_pred, W_out,
                                      xp, Gm, Wo4, Wh4, Wp4);

    for (int L = 0; L <= Sn; ++L)
        rnnt_step<<<256, 320, 0, stream>>>(xp, Gm, Wo4, Wh4, Wp4,
                                           b_out, b_lstm, b_pred, outlen,
                                           cb, db, gb, pb, rec,
                                           (float*)d_out, L);
}